// Round 7
// baseline (707.532 us; speedup 1.0000x reference)
//
#include <hip/hip_runtime.h>
#include <hip/hip_bf16.h>

typedef float f32x4 __attribute__((ext_vector_type(4)));
typedef __bf16 bfv8 __attribute__((ext_vector_type(8)));

constexpr int Bc = 4, Sc = 2048, Ec = 1024, Hc = 16, Dc = 64;
constexpr int Mc = Bc * Sc;  // 8192 rows

__device__ __forceinline__ uint pkbf(float lo, float hi) {
  uint r;
  asm("v_cvt_pk_bf16_f32 %0, %1, %2" : "=v"(r) : "v"(lo), "v"(hi));
  return r;
}
__device__ __forceinline__ ushort f2bf(float f) {
  __hip_bfloat16 h = __float2bfloat16(f);
  return __builtin_bit_cast(ushort, h);
}

typedef __attribute__((address_space(1))) unsigned int as1_u32;
typedef __attribute__((address_space(3))) unsigned int as3_u32;
__device__ __forceinline__ void cp16(const ushort* g, ushort* l) {
  // async global->LDS, 16B per lane; LDS dest = wave-uniform base + lane*16
  __builtin_amdgcn_global_load_lds((as1_u32*)g, (as3_u32*)l, 16, 0, 0);
}

// ---------------- weight convert + transpose: W[K][N] f32 -> WT[N][K] bf16 ----
__global__ __launch_bounds__(256) void wcvt_kernel(const float* __restrict__ W,
                                                   ushort* __restrict__ WT,
                                                   int K, int N) {
  __shared__ float t[32][33];
  int k0 = blockIdx.x * 32, n0 = blockIdx.y * 32;
  int tx = threadIdx.x, ty = threadIdx.y;  // (32,8)
#pragma unroll
  for (int i = 0; i < 32; i += 8)
    t[ty + i][tx] = W[(size_t)(k0 + ty + i) * N + n0 + tx];
  __syncthreads();
#pragma unroll
  for (int i = 0; i < 32; i += 8)
    WT[(size_t)(n0 + ty + i) * K + k0 + tx] = f2bf(t[tx][ty + i]);
}

// ---------------- LayerNorm: row of 1024, one block per row ------------------
__global__ __launch_bounds__(256) void ln_kernel(const float* in,
                                                 const float* __restrict__ g,
                                                 const float* __restrict__ bb,
                                                 float* of, ushort* ob) {
  int row = blockIdx.x;
  int t = threadIdx.x;
  float4 x = reinterpret_cast<const float4*>(in + (size_t)row * Ec)[t];
  float s = x.x + x.y + x.z + x.w;
  float q = x.x * x.x + x.y * x.y + x.z * x.z + x.w * x.w;
#pragma unroll
  for (int o = 32; o > 0; o >>= 1) {
    s += __shfl_down(s, o);
    q += __shfl_down(q, o);
  }
  __shared__ float red[10];
  int wv = t >> 6;
  if ((t & 63) == 0) { red[wv] = s; red[4 + wv] = q; }
  __syncthreads();
  if (t == 0) {
    float S = red[0] + red[1] + red[2] + red[3];
    float Q = red[4] + red[5] + red[6] + red[7];
    float mu = S * (1.f / Ec);
    float var = Q * (1.f / Ec) - mu * mu;
    red[8] = mu;
    red[9] = rsqrtf(var + 1e-5f);
  }
  __syncthreads();
  float mu = red[8], rs = red[9];
  float4 gg = reinterpret_cast<const float4*>(g)[t];
  float4 b4 = reinterpret_cast<const float4*>(bb)[t];
  float4 y;
  y.x = (x.x - mu) * rs * gg.x + b4.x;
  y.y = (x.y - mu) * rs * gg.y + b4.y;
  y.z = (x.z - mu) * rs * gg.z + b4.z;
  y.w = (x.w - mu) * rs * gg.w + b4.w;
  reinterpret_cast<float4*>(of + (size_t)row * Ec)[t] = y;
  uint2 u;
  u.x = pkbf(y.x, y.y);
  u.y = pkbf(y.z, y.w);
  reinterpret_cast<uint2*>(ob + (size_t)row * Ec)[t] = u;
}

// ---------------- GEMM: C[M,N] = A[M,K](bf16) * BT[N,K]^T(bf16) + epilogue ---
// 128x128 tile, BK=64, LDS double-buffered, counted vmcnt(8) + raw s_barrier.
// MODE 0: fused QKV; MODE 1: f32 acc+bias+resid; MODE 2: bf16 gelu(acc+bias)
template <int MODE>
__global__ __launch_bounds__(256, 2) void gemm_kernel(
    int M, int N, int K, const ushort* __restrict__ A,
    const ushort* __restrict__ BT, const float* __restrict__ b0,
    const float* __restrict__ b1, const float* __restrict__ b2,
    const float* resid, float* outF, ushort* o0, ushort* o1, ushort* o2,
    float qscale) {
  __shared__ __align__(16) ushort As[2][128 * 64];
  __shared__ __align__(16) ushort Bs[2][128 * 64];
  const int tid = threadIdx.x;
  const int lane = tid & 63, wave = tid >> 6;
  const int wr = wave >> 1, wc = wave & 1;
  const int fr = lane & 15, fq = lane >> 4;
  const int nx = gridDim.x;
  int flat = blockIdx.x + nx * blockIdx.y;
  int cpx = (nx * gridDim.y) >> 3;
  int work = (flat & 7) * cpx + (flat >> 3);
  const int n0 = (work % nx) * 128, m0 = (work / nx) * 128;

  f32x4 acc[4][4];
#pragma unroll
  for (int i = 0; i < 4; i++)
#pragma unroll
    for (int j = 0; j < 4; j++) acc[i][j] = f32x4{0.f, 0.f, 0.f, 0.f};

  const int srow = tid >> 3;   // 0..31 (+32 per chunk)
  const int sslot = tid & 7;   // 16B slot within 128B row

  auto STAGE = [&](int p, int k0) {
#pragma unroll
    for (int c = 0; c < 4; ++c) {
      int row = c * 32 + srow;
      int scol = (sslot ^ (2 * (row & 3))) * 8;  // inverse-swizzled source
      cp16(A + (size_t)(m0 + row) * K + k0 + scol,
           &As[p][(c * 256 + wave * 64) * 8]);
      cp16(BT + (size_t)(n0 + row) * K + k0 + scol,
           &Bs[p][(c * 256 + wave * 64) * 8]);
    }
  };

  STAGE(0, 0);
  const int nt = K >> 6;
  for (int kt = 0; kt < nt; ++kt) {
    const int p = kt & 1;
    if (kt + 1 < nt) {
      STAGE(p ^ 1, (kt + 1) << 6);
      asm volatile("s_waitcnt vmcnt(8)" ::: "memory");  // tile kt landed
    } else {
      asm volatile("s_waitcnt vmcnt(0)" ::: "memory");
    }
    __builtin_amdgcn_s_barrier();
#pragma unroll
    for (int kk = 0; kk < 2; ++kk) {
      bfv8 af[4], bf[4];
#pragma unroll
      for (int m = 0; m < 4; m++) {
        int row = wr * 64 + m * 16 + fr;
        af[m] = *reinterpret_cast<const bfv8*>(
            &As[p][row * 64 + ((kk * 32 + fq * 8) ^ ((fr & 3) << 4))]);
      }
#pragma unroll
      for (int n = 0; n < 4; n++) {
        int row = wc * 64 + n * 16 + fr;
        bf[n] = *reinterpret_cast<const bfv8*>(
            &Bs[p][row * 64 + ((kk * 32 + fq * 8) ^ ((fr & 3) << 4))]);
      }
      __builtin_amdgcn_s_setprio(1);
#pragma unroll
      for (int m = 0; m < 4; m++)
#pragma unroll
        for (int n = 0; n < 4; n++)
          acc[m][n] =
              __builtin_amdgcn_mfma_f32_16x16x32_bf16(af[m], bf[n], acc[m][n], 0, 0, 0);
      __builtin_amdgcn_s_setprio(0);
    }
    __builtin_amdgcn_sched_barrier(0);
    __builtin_amdgcn_s_barrier();
  }

#pragma unroll
  for (int m = 0; m < 4; m++) {
#pragma unroll
    for (int n = 0; n < 4; n++) {
      const int row0 = m0 + wr * 64 + m * 16 + fq * 4;
      const int col = n0 + wc * 64 + n * 16 + fr;
      if constexpr (MODE == 0) {
        const int region = col >> 10, c1 = col & (Ec - 1);
        const int b = row0 >> 11, s0 = row0 & (Sc - 1);
        const int h = c1 >> 6, d = c1 & (Dc - 1);
        const float bb = (region == 0 ? b0 : region == 1 ? b1 : b2)[c1];
        if (region == 2) {
          uint2 u;
          u.x = pkbf(acc[m][n][0] + bb, acc[m][n][1] + bb);
          u.y = pkbf(acc[m][n][2] + bb, acc[m][n][3] + bb);
          *reinterpret_cast<uint2*>(
              &o2[(((size_t)b * Hc + h) * Dc + d) * Sc + s0]) = u;
        } else {
          ushort* dst = region ? o1 : o0;
          const float sc = region ? 1.f : qscale;
#pragma unroll
          for (int r = 0; r < 4; r++)
            dst[(((size_t)b * Hc + h) * Sc + s0 + r) * Dc + d] =
                f2bf((acc[m][n][r] + bb) * sc);
        }
      } else {
        const float bb = b0[col];
#pragma unroll
        for (int r = 0; r < 4; r++) {
          int row = row0 + r;
          float vacc = acc[m][n][r] + bb;
          if constexpr (MODE == 1) {
            size_t idx = (size_t)row * N + col;
            outF[idx] = vacc + resid[idx];
          } else {
            vacc = 0.5f * vacc * (1.f + erff(vacc * 0.70710678118f));
            o0[(size_t)row * N + col] = f2bf(vacc);
          }
        }
      }
    }
  }
}

// ---------------- Flash attention (32 q-rows per wave, 128 per block) --------
// q,k: [B,H,S,D] bf16 (q pre-scaled by log2e/sqrt(D)); vt: [B,H,D,S] bf16.
// Swapped QK^T; exp2-domain softmax; defer-max (THR=8 log2).
// T14 async-stage: K/V tile t+1 loaded to REGISTERS right after top barrier
// (hides HBM/L2 latency under tile-t compute), ds_written after bottom
// barrier into single-buffered XOR-swizzled LDS. Race-free 2-barrier loop.
__global__ __launch_bounds__(256, 4) void attn_kernel(const ushort* __restrict__ q,
                                                      const ushort* __restrict__ k,
                                                      const ushort* __restrict__ vt,
                                                      ushort* __restrict__ o) {
  int flat = blockIdx.x;                     // 1024 blocks
  int swz = (flat & 7) * 128 + (flat >> 3);  // XCD-chunked: 8 heads per XCD
  const int qb = swz & 15;                   // 16 q-blocks of 128 rows
  const int bh = swz >> 4;
  const int tid = threadIdx.x, lane = tid & 63, wave = tid >> 6;
  const int fr = lane & 15, fq = lane >> 4;
  const size_t base = (size_t)bh * Sc * Dc;
  const int q0 = qb * 128 + wave * 32;

  __shared__ __align__(16) ushort Ks[64 * 64];     // [key][d], XOR-swizzled
  __shared__ __align__(16) ushort Vt[64 * 64];     // [d][key], XOR-swizzled
  __shared__ __align__(16) ushort Ps[4][16 * 72];  // per-wave P tile

  bfv8 qf0[2], qf1[2];
#pragma unroll
  for (int f = 0; f < 2; ++f) {
    const ushort* qp = q + base + (size_t)(q0 + f * 16 + fr) * Dc + fq * 8;
    qf0[f] = *reinterpret_cast<const bfv8*>(qp);
    qf1[f] = *reinterpret_cast<const bfv8*>(qp + 32);
  }

  f32x4 oacc[2][4];  // [frag][dtile]
#pragma unroll
  for (int f = 0; f < 2; ++f)
#pragma unroll
    for (int d = 0; d < 4; ++d) oacc[f][d] = f32x4{0.f, 0.f, 0.f, 0.f};
  float mrow[2] = {-3e38f, -3e38f};
  float lrow[2] = {0.f, 0.f};

  const int r8 = tid >> 3;  // staging row 0..31
  const int c8 = tid & 7;   // staging 16B chunk

  // register staging (T14): global addrs are UNswizzled; swizzle applied on
  // the ds_write side (and matched by frag reads).
  const ushort* kg0 = k + base + (size_t)r8 * Dc + c8 * 8;
  const ushort* vg0 = vt + base + (size_t)r8 * Sc + c8 * 8;
  const int wof0 = r8 * 64 + ((c8 ^ (r8 & 7)) * 8);  // ushort offset, +2048 for i=1
  int4 kr[2], vr[2];

  auto LD = [&](int key0) {
#pragma unroll
    for (int i = 0; i < 2; ++i) {
      kr[i] = *reinterpret_cast<const int4*>(kg0 + (size_t)(key0 + i * 32) * Dc);
      vr[i] = *reinterpret_cast<const int4*>(vg0 + (size_t)(i * 32) * Sc + key0);
    }
  };
  auto STORE = [&]() {
#pragma unroll
    for (int i = 0; i < 2; ++i) {
      *reinterpret_cast<int4*>(&Ks[wof0 + i * 2048]) = kr[i];
      *reinterpret_cast<int4*>(&Vt[wof0 + i * 2048]) = vr[i];
    }
  };

  const int sA = (fq ^ (fr & 7)) * 8;        // swizzled read offset, chunks 0-3
  const int sB = ((fq + 4) ^ (fr & 7)) * 8;  // chunks 4-7

  LD(0);
  STORE();  // compiler inserts vmcnt wait before ds_write
  constexpr int NT = Sc / 64;
  for (int kt = 0; kt < NT; ++kt) {
    __syncthreads();  // staged writes visible to all waves
    if (kt + 1 < NT) LD((kt + 1) * 64);  // async loads overlap compute below

    bfv8 kf0[4], kf1[4], vf0[4], vf1[4];
#pragma unroll
    for (int t = 0; t < 4; ++t) {
      int e = (t * 16 + fr) * 64;
      kf0[t] = *reinterpret_cast<const bfv8*>(&Ks[e + sA]);
      kf1[t] = *reinterpret_cast<const bfv8*>(&Ks[e + sB]);
      vf0[t] = *reinterpret_cast<const bfv8*>(&Vt[e + sA]);
      vf1[t] = *reinterpret_cast<const bfv8*>(&Vt[e + sB]);
    }

#pragma unroll
    for (int f = 0; f < 2; ++f) {
      f32x4 sf[4];
      __builtin_amdgcn_s_setprio(1);
#pragma unroll
      for (int t = 0; t < 4; ++t) {
        sf[t] = f32x4{0.f, 0.f, 0.f, 0.f};
        sf[t] = __builtin_amdgcn_mfma_f32_16x16x32_bf16(kf0[t], qf0[f], sf[t], 0, 0, 0);
        sf[t] = __builtin_amdgcn_mfma_f32_16x16x32_bf16(kf1[t], qf1[f], sf[t], 0, 0, 0);
      }
      __builtin_amdgcn_s_setprio(0);
      // lane holds S[q=fr][key = t*16 + fq*4 + r], log2 domain
      float mt0 = fmaxf(fmaxf(sf[0][0], sf[0][1]), fmaxf(sf[0][2], sf[0][3]));
      float mt1 = fmaxf(fmaxf(sf[1][0], sf[1][1]), fmaxf(sf[1][2], sf[1][3]));
      float mt2 = fmaxf(fmaxf(sf[2][0], sf[2][1]), fmaxf(sf[2][2], sf[2][3]));
      float mt3 = fmaxf(fmaxf(sf[3][0], sf[3][1]), fmaxf(sf[3][2], sf[3][3]));
      float pmax = fmaxf(fmaxf(mt0, mt1), fmaxf(mt2, mt3));
      float m = mrow[f];
      float mnew = m;
      if (!__all(pmax <= m + 8.f)) {
        float mt = fmaxf(pmax, __shfl_xor(pmax, 16));
        mt = fmaxf(mt, __shfl_xor(mt, 32));
        mnew = fmaxf(m, mt);
        float alpha = __builtin_amdgcn_exp2f(m - mnew);
        float ar[4];
#pragma unroll
        for (int r = 0; r < 4; ++r) ar[r] = __shfl(alpha, fq * 4 + r);
#pragma unroll
        for (int d = 0; d < 4; ++d)
#pragma unroll
          for (int r = 0; r < 4; ++r) oacc[f][d][r] *= ar[r];
        lrow[f] *= alpha;
        mrow[f] = mnew;
      }
      float p[4][4];
      float rsum = 0.f;
#pragma unroll
      for (int t = 0; t < 4; ++t) {
#pragma unroll
        for (int r = 0; r < 4; ++r) {
          p[t][r] = __builtin_amdgcn_exp2f(sf[t][r] - mnew);
        }
        rsum += (p[t][0] + p[t][1]) + (p[t][2] + p[t][3]);
      }
      rsum += __shfl_xor(rsum, 16);
      rsum += __shfl_xor(rsum, 32);
      lrow[f] += rsum;
      ushort* pw = &Ps[wave][0];
#pragma unroll
      for (int t = 0; t < 4; ++t) {
        uint2 pu;
        pu.x = pkbf(p[t][0], p[t][1]);
        pu.y = pkbf(p[t][2], p[t][3]);
        *reinterpret_cast<uint2*>(&pw[fr * 72 + t * 16 + fq * 4]) = pu;
      }
      bfv8 pf0 = *reinterpret_cast<const bfv8*>(&pw[fr * 72 + fq * 8]);
      bfv8 pf1 = *reinterpret_cast<const bfv8*>(&pw[fr * 72 + 32 + fq * 8]);
      __builtin_amdgcn_s_setprio(1);
#pragma unroll
      for (int d = 0; d < 4; ++d) {
        oacc[f][d] = __builtin_amdgcn_mfma_f32_16x16x32_bf16(pf0, vf0[d], oacc[f][d], 0, 0, 0);
        oacc[f][d] = __builtin_amdgcn_mfma_f32_16x16x32_bf16(pf1, vf1[d], oacc[f][d], 0, 0, 0);
      }
      __builtin_amdgcn_s_setprio(0);
    }
    __syncthreads();  // all waves done reading LDS tile kt (loads also landed)
    if (kt + 1 < NT) STORE();
  }

  const int b = bh >> 4, h = bh & 15;
#pragma unroll
  for (int f = 0; f < 2; ++f) {
    float linv[4];
#pragma unroll
    for (int r = 0; r < 4; ++r) linv[r] = 1.f / __shfl(lrow[f], fq * 4 + r);
#pragma unroll
    for (int d = 0; d < 4; ++d)
#pragma unroll
      for (int r = 0; r < 4; ++r) {
        int sIdx = q0 + f * 16 + fq * 4 + r;
        o[((size_t)(b * Sc + sIdx)) * Ec + h * 64 + d * 16 + fr] =
            f2bf(oacc[f][d][r] * linv[r]);
      }
  }
}

// -----------------------------------------------------------------------------
extern "C" void kernel_launch(void* const* d_in, const int* in_sizes, int n_in,
                              void* d_out, int out_size, void* d_ws, size_t ws_size,
                              hipStream_t stream) {
  const float* inp = (const float*)d_in[0];
  const float* ln1g = (const float*)d_in[1];
  const float* ln1b = (const float*)d_in[2];
  const float* Wq = (const float*)d_in[3];
  const float* bq = (const float*)d_in[4];
  const float* Wk = (const float*)d_in[5];
  const float* bk = (const float*)d_in[6];
  const float* Wv = (const float*)d_in[7];
  const float* bv = (const float*)d_in[8];
  const float* Wo = (const float*)d_in[9];
  const float* bo = (const float*)d_in[10];
  const float* ln2g = (const float*)d_in[11];
  const float* ln2b = (const float*)d_in[12];
  const float* W1 = (const float*)d_in[13];
  const float* b1 = (const float*)d_in[14];
  const float* W2 = (const float*)d_in[15];
  const float* b2 = (const float*)d_in[16];

  char* wsb = (char*)d_ws;
  size_t off = 0;
  auto alloc = [&](size_t bytes) {
    char* p = wsb + off;
    off += (bytes + 255) & ~(size_t)255;
    return p;
  };
  float* xf = (float*)alloc((size_t)Mc * Ec * 4);
  ushort* xb = (ushort*)alloc((size_t)Mc * Ec * 2);
  ushort* qbuf = (ushort*)alloc((size_t)Mc * Ec * 2);
  ushort* kbuf = (ushort*)alloc((size_t)Mc * Ec * 2);
  ushort* vtbuf = (ushort*)alloc((size_t)Mc * Ec * 2);
  ushort* abuf = (ushort*)alloc((size_t)Mc * Ec * 2);
  ushort* h1 = (ushort*)alloc((size_t)Mc * 2 * Ec * 2);
  ushort* WqkvT = (ushort*)alloc((size_t)3 * Ec * Ec * 2);  // [3E][E]
  ushort* WoT = (ushort*)alloc((size_t)Ec * Ec * 2);
  ushort* W1T = (ushort*)alloc((size_t)Ec * 2 * Ec * 2);
  ushort* W2T = (ushort*)alloc((size_t)Ec * 2 * Ec * 2);
  (void)in_sizes; (void)n_in; (void)out_size; (void)ws_size;

  dim3 tb(32, 8);
  wcvt_kernel<<<dim3(Ec / 32, Ec / 32), tb, 0, stream>>>(Wq, WqkvT, Ec, Ec);
  wcvt_kernel<<<dim3(Ec / 32, Ec / 32), tb, 0, stream>>>(Wk, WqkvT + (size_t)Ec * Ec, Ec, Ec);
  wcvt_kernel<<<dim3(Ec / 32, Ec / 32), tb, 0, stream>>>(Wv, WqkvT + (size_t)2 * Ec * Ec, Ec, Ec);
  wcvt_kernel<<<dim3(Ec / 32, Ec / 32), tb, 0, stream>>>(Wo, WoT, Ec, Ec);
  wcvt_kernel<<<dim3(Ec / 32, 2 * Ec / 32), tb, 0, stream>>>(W1, W1T, Ec, 2 * Ec);
  wcvt_kernel<<<dim3(2 * Ec / 32, Ec / 32), tb, 0, stream>>>(W2, W2T, 2 * Ec, Ec);

  ln_kernel<<<Mc, 256, 0, stream>>>(inp, ln1g, ln1b, xf, xb);

  // Fused QKV: N=3072. Q pre-scale (1/sqrt(D))*log2(e) -> exp2-domain softmax
  gemm_kernel<0><<<dim3(3 * Ec / 128, Mc / 128), 256, 0, stream>>>(
      Mc, 3 * Ec, Ec, xb, WqkvT, bq, bk, bv, nullptr, nullptr, qbuf, kbuf,
      vtbuf, 0.18033688f);

  attn_kernel<<<Bc * Hc * (Sc / 128), 256, 0, stream>>>(qbuf, kbuf, vtbuf, abuf);

  gemm_kernel<1><<<dim3(Ec / 128, Mc / 128), 256, 0, stream>>>(
      Mc, Ec, Ec, abuf, WoT, bo, nullptr, nullptr, xf, xf, nullptr, nullptr,
      nullptr, 1.f);

  ln_kernel<<<Mc, 256, 0, stream>>>(xf, ln2g, ln2b, xf, xb);

  gemm_kernel<2><<<dim3(2 * Ec / 128, Mc / 128), 256, 0, stream>>>(
      Mc, 2 * Ec, Ec, xb, W1T, b1, nullptr, nullptr, nullptr, nullptr, h1,
      nullptr, nullptr, 1.f);

  gemm_kernel<1><<<dim3(Ec / 128, Mc / 128), 256, 0, stream>>>(
      Mc, Ec, 2 * Ec, h1, W2T, b2, nullptr, nullptr, xf, (float*)d_out,
      nullptr, nullptr, nullptr, 1.f);
}

// Round 8
// 435.249 us; speedup vs baseline: 1.6256x; 1.6256x over previous
//
#include <hip/hip_runtime.h>
#include <hip/hip_bf16.h>

typedef float f32x4 __attribute__((ext_vector_type(4)));
typedef __bf16 bfv8 __attribute__((ext_vector_type(8)));

constexpr int Bc = 4, Sc = 2048, Ec = 1024, Hc = 16, Dc = 64;
constexpr int Mc = Bc * Sc;  // 8192 rows

__device__ __forceinline__ uint pkbf(float lo, float hi) {
  uint r;
  asm("v_cvt_pk_bf16_f32 %0, %1, %2" : "=v"(r) : "v"(lo), "v"(hi));
  return r;
}
__device__ __forceinline__ ushort f2bf(float f) {
  __hip_bfloat16 h = __float2bfloat16(f);
  return __builtin_bit_cast(ushort, h);
}

typedef __attribute__((address_space(1))) unsigned int as1_u32;
typedef __attribute__((address_space(3))) unsigned int as3_u32;
__device__ __forceinline__ void cp16(const ushort* g, ushort* l) {
  // async global->LDS, 16B per lane; LDS dest = wave-uniform base + lane*16
  __builtin_amdgcn_global_load_lds((as1_u32*)g, (as3_u32*)l, 16, 0, 0);
}

// ---------------- weight convert + transpose: W[K][N] f32 -> WT[N][K] bf16 ----
__global__ __launch_bounds__(256) void wcvt_kernel(const float* __restrict__ W,
                                                   ushort* __restrict__ WT,
                                                   int K, int N) {
  __shared__ float t[32][33];
  int k0 = blockIdx.x * 32, n0 = blockIdx.y * 32;
  int tx = threadIdx.x, ty = threadIdx.y;  // (32,8)
#pragma unroll
  for (int i = 0; i < 32; i += 8)
    t[ty + i][tx] = W[(size_t)(k0 + ty + i) * N + n0 + tx];
  __syncthreads();
#pragma unroll
  for (int i = 0; i < 32; i += 8)
    WT[(size_t)(n0 + ty + i) * K + k0 + tx] = f2bf(t[tx][ty + i]);
}

// ---------------- LayerNorm: row of 1024, one block per row ------------------
__global__ __launch_bounds__(256) void ln_kernel(const float* in,
                                                 const float* __restrict__ g,
                                                 const float* __restrict__ bb,
                                                 float* of, ushort* ob) {
  int row = blockIdx.x;
  int t = threadIdx.x;
  float4 x = reinterpret_cast<const float4*>(in + (size_t)row * Ec)[t];
  float s = x.x + x.y + x.z + x.w;
  float q = x.x * x.x + x.y * x.y + x.z * x.z + x.w * x.w;
#pragma unroll
  for (int o = 32; o > 0; o >>= 1) {
    s += __shfl_down(s, o);
    q += __shfl_down(q, o);
  }
  __shared__ float red[10];
  int wv = t >> 6;
  if ((t & 63) == 0) { red[wv] = s; red[4 + wv] = q; }
  __syncthreads();
  if (t == 0) {
    float S = red[0] + red[1] + red[2] + red[3];
    float Q = red[4] + red[5] + red[6] + red[7];
    float mu = S * (1.f / Ec);
    float var = Q * (1.f / Ec) - mu * mu;
    red[8] = mu;
    red[9] = rsqrtf(var + 1e-5f);
  }
  __syncthreads();
  float mu = red[8], rs = red[9];
  float4 gg = reinterpret_cast<const float4*>(g)[t];
  float4 b4 = reinterpret_cast<const float4*>(bb)[t];
  float4 y;
  y.x = (x.x - mu) * rs * gg.x + b4.x;
  y.y = (x.y - mu) * rs * gg.y + b4.y;
  y.z = (x.z - mu) * rs * gg.z + b4.z;
  y.w = (x.w - mu) * rs * gg.w + b4.w;
  reinterpret_cast<float4*>(of + (size_t)row * Ec)[t] = y;
  uint2 u;
  u.x = pkbf(y.x, y.y);
  u.y = pkbf(y.z, y.w);
  reinterpret_cast<uint2*>(ob + (size_t)row * Ec)[t] = u;
}

// ---------------- GEMM: C[M,N] = A[M,K](bf16) * BT[N,K]^T(bf16) + epilogue ---
// 128x128 tile, BK=64, LDS double-buffered, counted vmcnt(8) + raw s_barrier.
// MODE 0: fused QKV; MODE 1: f32 acc+bias+resid; MODE 2: bf16 gelu(acc+bias)
template <int MODE>
__global__ __launch_bounds__(256, 2) void gemm_kernel(
    int M, int N, int K, const ushort* __restrict__ A,
    const ushort* __restrict__ BT, const float* __restrict__ b0,
    const float* __restrict__ b1, const float* __restrict__ b2,
    const float* resid, float* outF, ushort* o0, ushort* o1, ushort* o2,
    float qscale) {
  __shared__ __align__(16) ushort As[2][128 * 64];
  __shared__ __align__(16) ushort Bs[2][128 * 64];
  const int tid = threadIdx.x;
  const int lane = tid & 63, wave = tid >> 6;
  const int wr = wave >> 1, wc = wave & 1;
  const int fr = lane & 15, fq = lane >> 4;
  const int nx = gridDim.x;
  int flat = blockIdx.x + nx * blockIdx.y;
  int cpx = (nx * gridDim.y) >> 3;
  int work = (flat & 7) * cpx + (flat >> 3);
  const int n0 = (work % nx) * 128, m0 = (work / nx) * 128;

  f32x4 acc[4][4];
#pragma unroll
  for (int i = 0; i < 4; i++)
#pragma unroll
    for (int j = 0; j < 4; j++) acc[i][j] = f32x4{0.f, 0.f, 0.f, 0.f};

  const int srow = tid >> 3;   // 0..31 (+32 per chunk)
  const int sslot = tid & 7;   // 16B slot within 128B row

  auto STAGE = [&](int p, int k0) {
#pragma unroll
    for (int c = 0; c < 4; ++c) {
      int row = c * 32 + srow;
      int scol = (sslot ^ (2 * (row & 3))) * 8;  // inverse-swizzled source
      cp16(A + (size_t)(m0 + row) * K + k0 + scol,
           &As[p][(c * 256 + wave * 64) * 8]);
      cp16(BT + (size_t)(n0 + row) * K + k0 + scol,
           &Bs[p][(c * 256 + wave * 64) * 8]);
    }
  };

  STAGE(0, 0);
  const int nt = K >> 6;
  for (int kt = 0; kt < nt; ++kt) {
    const int p = kt & 1;
    if (kt + 1 < nt) {
      STAGE(p ^ 1, (kt + 1) << 6);
      asm volatile("s_waitcnt vmcnt(8)" ::: "memory");  // tile kt landed
    } else {
      asm volatile("s_waitcnt vmcnt(0)" ::: "memory");
    }
    __builtin_amdgcn_s_barrier();
#pragma unroll
    for (int kk = 0; kk < 2; ++kk) {
      bfv8 af[4], bf[4];
#pragma unroll
      for (int m = 0; m < 4; m++) {
        int row = wr * 64 + m * 16 + fr;
        af[m] = *reinterpret_cast<const bfv8*>(
            &As[p][row * 64 + ((kk * 32 + fq * 8) ^ ((fr & 3) << 4))]);
      }
#pragma unroll
      for (int n = 0; n < 4; n++) {
        int row = wc * 64 + n * 16 + fr;
        bf[n] = *reinterpret_cast<const bfv8*>(
            &Bs[p][row * 64 + ((kk * 32 + fq * 8) ^ ((fr & 3) << 4))]);
      }
      __builtin_amdgcn_s_setprio(1);
#pragma unroll
      for (int m = 0; m < 4; m++)
#pragma unroll
        for (int n = 0; n < 4; n++)
          acc[m][n] =
              __builtin_amdgcn_mfma_f32_16x16x32_bf16(af[m], bf[n], acc[m][n], 0, 0, 0);
      __builtin_amdgcn_s_setprio(0);
    }
    __builtin_amdgcn_sched_barrier(0);
    __builtin_amdgcn_s_barrier();
  }

#pragma unroll
  for (int m = 0; m < 4; m++) {
#pragma unroll
    for (int n = 0; n < 4; n++) {
      const int row0 = m0 + wr * 64 + m * 16 + fq * 4;
      const int col = n0 + wc * 64 + n * 16 + fr;
      if constexpr (MODE == 0) {
        const int region = col >> 10, c1 = col & (Ec - 1);
        const int b = row0 >> 11, s0 = row0 & (Sc - 1);
        const int h = c1 >> 6, d = c1 & (Dc - 1);
        const float bb = (region == 0 ? b0 : region == 1 ? b1 : b2)[c1];
        if (region == 2) {
          uint2 u;
          u.x = pkbf(acc[m][n][0] + bb, acc[m][n][1] + bb);
          u.y = pkbf(acc[m][n][2] + bb, acc[m][n][3] + bb);
          *reinterpret_cast<uint2*>(
              &o2[(((size_t)b * Hc + h) * Dc + d) * Sc + s0]) = u;
        } else {
          ushort* dst = region ? o1 : o0;
          const float sc = region ? 1.f : qscale;
#pragma unroll
          for (int r = 0; r < 4; r++)
            dst[(((size_t)b * Hc + h) * Sc + s0 + r) * Dc + d] =
                f2bf((acc[m][n][r] + bb) * sc);
        }
      } else {
        const float bb = b0[col];
#pragma unroll
        for (int r = 0; r < 4; r++) {
          int row = row0 + r;
          float vacc = acc[m][n][r] + bb;
          if constexpr (MODE == 1) {
            size_t idx = (size_t)row * N + col;
            outF[idx] = vacc + resid[idx];
          } else {
            vacc = 0.5f * vacc * (1.f + erff(vacc * 0.70710678118f));
            o0[(size_t)row * N + col] = f2bf(vacc);
          }
        }
      }
    }
  }
}

// ---------------- Flash attention (32 q-rows per wave, 128 per block) --------
// q,k: [B,H,S,D] bf16 (q pre-scaled by log2e/sqrt(D)); vt: [B,H,D,S] bf16.
// Swapped QK^T; exp2-domain softmax; defer-max (THR=8 log2).
// T14 async-stage: K/V tile t+1 loaded to REGISTERS right after top barrier
// (hides HBM/L2 latency under tile-t compute), ds_written after bottom
// barrier into single-buffered XOR-swizzled LDS. Race-free 2-barrier loop.
// NOTE: no launch_bounds occupancy clamp — R7's (256,4) forced 64 VGPR and
// spilled the staging regs to scratch (1 GB of WRITE_SIZE).
__global__ __launch_bounds__(256) void attn_kernel(const ushort* __restrict__ q,
                                                   const ushort* __restrict__ k,
                                                   const ushort* __restrict__ vt,
                                                   ushort* __restrict__ o) {
  int flat = blockIdx.x;                     // 1024 blocks
  int swz = (flat & 7) * 128 + (flat >> 3);  // XCD-chunked: 8 heads per XCD
  const int qb = swz & 15;                   // 16 q-blocks of 128 rows
  const int bh = swz >> 4;
  const int tid = threadIdx.x, lane = tid & 63, wave = tid >> 6;
  const int fr = lane & 15, fq = lane >> 4;
  const size_t base = (size_t)bh * Sc * Dc;
  const int q0 = qb * 128 + wave * 32;

  __shared__ __align__(16) ushort Ks[64 * 64];     // [key][d], XOR-swizzled
  __shared__ __align__(16) ushort Vt[64 * 64];     // [d][key], XOR-swizzled
  __shared__ __align__(16) ushort Ps[4][16 * 72];  // per-wave P tile

  bfv8 qf0[2], qf1[2];
#pragma unroll
  for (int f = 0; f < 2; ++f) {
    const ushort* qp = q + base + (size_t)(q0 + f * 16 + fr) * Dc + fq * 8;
    qf0[f] = *reinterpret_cast<const bfv8*>(qp);
    qf1[f] = *reinterpret_cast<const bfv8*>(qp + 32);
  }

  f32x4 oacc[2][4];  // [frag][dtile]
#pragma unroll
  for (int f = 0; f < 2; ++f)
#pragma unroll
    for (int d = 0; d < 4; ++d) oacc[f][d] = f32x4{0.f, 0.f, 0.f, 0.f};
  float mrow[2] = {-3e38f, -3e38f};
  float lrow[2] = {0.f, 0.f};

  const int r8 = tid >> 3;  // staging row 0..31
  const int c8 = tid & 7;   // staging 16B chunk

  // register staging (T14): global addrs are UNswizzled; swizzle applied on
  // the ds_write side (and matched by frag reads).
  const ushort* kg0 = k + base + (size_t)r8 * Dc + c8 * 8;
  const ushort* vg0 = vt + base + (size_t)r8 * Sc + c8 * 8;
  const int wof0 = r8 * 64 + ((c8 ^ (r8 & 7)) * 8);  // ushort offset, +2048 for i=1
  int4 kr[2], vr[2];

  auto LD = [&](int key0) {
#pragma unroll
    for (int i = 0; i < 2; ++i) {
      kr[i] = *reinterpret_cast<const int4*>(kg0 + (size_t)(key0 + i * 32) * Dc);
      vr[i] = *reinterpret_cast<const int4*>(vg0 + (size_t)(i * 32) * Sc + key0);
    }
  };
  auto STORE = [&]() {
#pragma unroll
    for (int i = 0; i < 2; ++i) {
      *reinterpret_cast<int4*>(&Ks[wof0 + i * 2048]) = kr[i];
      *reinterpret_cast<int4*>(&Vt[wof0 + i * 2048]) = vr[i];
    }
  };

  const int sA = (fq ^ (fr & 7)) * 8;        // swizzled read offset, chunks 0-3
  const int sB = ((fq + 4) ^ (fr & 7)) * 8;  // chunks 4-7

  LD(0);
  STORE();  // compiler inserts vmcnt wait before ds_write
  constexpr int NT = Sc / 64;
  for (int kt = 0; kt < NT; ++kt) {
    __syncthreads();  // staged writes visible to all waves
    if (kt + 1 < NT) LD((kt + 1) * 64);  // async loads overlap compute below

    bfv8 kf0[4], kf1[4], vf0[4], vf1[4];
#pragma unroll
    for (int t = 0; t < 4; ++t) {
      int e = (t * 16 + fr) * 64;
      kf0[t] = *reinterpret_cast<const bfv8*>(&Ks[e + sA]);
      kf1[t] = *reinterpret_cast<const bfv8*>(&Ks[e + sB]);
      vf0[t] = *reinterpret_cast<const bfv8*>(&Vt[e + sA]);
      vf1[t] = *reinterpret_cast<const bfv8*>(&Vt[e + sB]);
    }

#pragma unroll
    for (int f = 0; f < 2; ++f) {
      f32x4 sf[4];
      __builtin_amdgcn_s_setprio(1);
#pragma unroll
      for (int t = 0; t < 4; ++t) {
        sf[t] = f32x4{0.f, 0.f, 0.f, 0.f};
        sf[t] = __builtin_amdgcn_mfma_f32_16x16x32_bf16(kf0[t], qf0[f], sf[t], 0, 0, 0);
        sf[t] = __builtin_amdgcn_mfma_f32_16x16x32_bf16(kf1[t], qf1[f], sf[t], 0, 0, 0);
      }
      __builtin_amdgcn_s_setprio(0);
      // lane holds S[q=fr][key = t*16 + fq*4 + r], log2 domain
      float mt0 = fmaxf(fmaxf(sf[0][0], sf[0][1]), fmaxf(sf[0][2], sf[0][3]));
      float mt1 = fmaxf(fmaxf(sf[1][0], sf[1][1]), fmaxf(sf[1][2], sf[1][3]));
      float mt2 = fmaxf(fmaxf(sf[2][0], sf[2][1]), fmaxf(sf[2][2], sf[2][3]));
      float mt3 = fmaxf(fmaxf(sf[3][0], sf[3][1]), fmaxf(sf[3][2], sf[3][3]));
      float pmax = fmaxf(fmaxf(mt0, mt1), fmaxf(mt2, mt3));
      float m = mrow[f];
      float mnew = m;
      if (!__all(pmax <= m + 8.f)) {
        float mt = fmaxf(pmax, __shfl_xor(pmax, 16));
        mt = fmaxf(mt, __shfl_xor(mt, 32));
        mnew = fmaxf(m, mt);
        float alpha = __builtin_amdgcn_exp2f(m - mnew);
        float ar[4];
#pragma unroll
        for (int r = 0; r < 4; ++r) ar[r] = __shfl(alpha, fq * 4 + r);
#pragma unroll
        for (int d = 0; d < 4; ++d)
#pragma unroll
          for (int r = 0; r < 4; ++r) oacc[f][d][r] *= ar[r];
        lrow[f] *= alpha;
        mrow[f] = mnew;
      }
      float p[4][4];
      float rsum = 0.f;
#pragma unroll
      for (int t = 0; t < 4; ++t) {
#pragma unroll
        for (int r = 0; r < 4; ++r) {
          p[t][r] = __builtin_amdgcn_exp2f(sf[t][r] - mnew);
        }
        rsum += (p[t][0] + p[t][1]) + (p[t][2] + p[t][3]);
      }
      rsum += __shfl_xor(rsum, 16);
      rsum += __shfl_xor(rsum, 32);
      lrow[f] += rsum;
      ushort* pw = &Ps[wave][0];
#pragma unroll
      for (int t = 0; t < 4; ++t) {
        uint2 pu;
        pu.x = pkbf(p[t][0], p[t][1]);
        pu.y = pkbf(p[t][2], p[t][3]);
        *reinterpret_cast<uint2*>(&pw[fr * 72 + t * 16 + fq * 4]) = pu;
      }
      bfv8 pf0 = *reinterpret_cast<const bfv8*>(&pw[fr * 72 + fq * 8]);
      bfv8 pf1 = *reinterpret_cast<const bfv8*>(&pw[fr * 72 + 32 + fq * 8]);
      __builtin_amdgcn_s_setprio(1);
#pragma unroll
      for (int d = 0; d < 4; ++d) {
        oacc[f][d] = __builtin_amdgcn_mfma_f32_16x16x32_bf16(pf0, vf0[d], oacc[f][d], 0, 0, 0);
        oacc[f][d] = __builtin_amdgcn_mfma_f32_16x16x32_bf16(pf1, vf1[d], oacc[f][d], 0, 0, 0);
      }
      __builtin_amdgcn_s_setprio(0);
    }
    __syncthreads();  // all waves done reading LDS tile kt (loads also landed)
    if (kt + 1 < NT) STORE();
  }

  const int b = bh >> 4, h = bh & 15;
#pragma unroll
  for (int f = 0; f < 2; ++f) {
    float linv[4];
#pragma unroll
    for (int r = 0; r < 4; ++r) linv[r] = 1.f / __shfl(lrow[f], fq * 4 + r);
#pragma unroll
    for (int d = 0; d < 4; ++d)
#pragma unroll
      for (int r = 0; r < 4; ++r) {
        int sIdx = q0 + f * 16 + fq * 4 + r;
        o[((size_t)(b * Sc + sIdx)) * Ec + h * 64 + d * 16 + fr] =
            f2bf(oacc[f][d][r] * linv[r]);
      }
  }
}

// -----------------------------------------------------------------------------
extern "C" void kernel_launch(void* const* d_in, const int* in_sizes, int n_in,
                              void* d_out, int out_size, void* d_ws, size_t ws_size,
                              hipStream_t stream) {
  const float* inp = (const float*)d_in[0];
  const float* ln1g = (const float*)d_in[1];
  const float* ln1b = (const float*)d_in[2];
  const float* Wq = (const float*)d_in[3];
  const float* bq = (const float*)d_in[4];
  const float* Wk = (const float*)d_in[5];
  const float* bk = (const float*)d_in[6];
  const float* Wv = (const float*)d_in[7];
  const float* bv = (const float*)d_in[8];
  const float* Wo = (const float*)d_in[9];
  const float* bo = (const float*)d_in[10];
  const float* ln2g = (const float*)d_in[11];
  const float* ln2b = (const float*)d_in[12];
  const float* W1 = (const float*)d_in[13];
  const float* b1 = (const float*)d_in[14];
  const float* W2 = (const float*)d_in[15];
  const float* b2 = (const float*)d_in[16];

  char* wsb = (char*)d_ws;
  size_t off = 0;
  auto alloc = [&](size_t bytes) {
    char* p = wsb + off;
    off += (bytes + 255) & ~(size_t)255;
    return p;
  };
  float* xf = (float*)alloc((size_t)Mc * Ec * 4);
  ushort* xb = (ushort*)alloc((size_t)Mc * Ec * 2);
  ushort* qbuf = (ushort*)alloc((size_t)Mc * Ec * 2);
  ushort* kbuf = (ushort*)alloc((size_t)Mc * Ec * 2);
  ushort* vtbuf = (ushort*)alloc((size_t)Mc * Ec * 2);
  ushort* abuf = (ushort*)alloc((size_t)Mc * Ec * 2);
  ushort* h1 = (ushort*)alloc((size_t)Mc * 2 * Ec * 2);
  ushort* WqkvT = (ushort*)alloc((size_t)3 * Ec * Ec * 2);  // [3E][E]
  ushort* WoT = (ushort*)alloc((size_t)Ec * Ec * 2);
  ushort* W1T = (ushort*)alloc((size_t)Ec * 2 * Ec * 2);
  ushort* W2T = (ushort*)alloc((size_t)Ec * 2 * Ec * 2);
  (void)in_sizes; (void)n_in; (void)out_size; (void)ws_size;

  dim3 tb(32, 8);
  wcvt_kernel<<<dim3(Ec / 32, Ec / 32), tb, 0, stream>>>(Wq, WqkvT, Ec, Ec);
  wcvt_kernel<<<dim3(Ec / 32, Ec / 32), tb, 0, stream>>>(Wk, WqkvT + (size_t)Ec * Ec, Ec, Ec);
  wcvt_kernel<<<dim3(Ec / 32, Ec / 32), tb, 0, stream>>>(Wv, WqkvT + (size_t)2 * Ec * Ec, Ec, Ec);
  wcvt_kernel<<<dim3(Ec / 32, Ec / 32), tb, 0, stream>>>(Wo, WoT, Ec, Ec);
  wcvt_kernel<<<dim3(Ec / 32, 2 * Ec / 32), tb, 0, stream>>>(W1, W1T, Ec, 2 * Ec);
  wcvt_kernel<<<dim3(2 * Ec / 32, Ec / 32), tb, 0, stream>>>(W2, W2T, 2 * Ec, Ec);

  ln_kernel<<<Mc, 256, 0, stream>>>(inp, ln1g, ln1b, xf, xb);

  // Fused QKV: N=3072. Q pre-scale (1/sqrt(D))*log2(e) -> exp2-domain softmax
  gemm_kernel<0><<<dim3(3 * Ec / 128, Mc / 128), 256, 0, stream>>>(
      Mc, 3 * Ec, Ec, xb, WqkvT, bq, bk, bv, nullptr, nullptr, qbuf, kbuf,
      vtbuf, 0.18033688f);

  attn_kernel<<<Bc * Hc * (Sc / 128), 256, 0, stream>>>(qbuf, kbuf, vtbuf, abuf);

  gemm_kernel<1><<<dim3(Ec / 128, Mc / 128), 256, 0, stream>>>(
      Mc, Ec, Ec, abuf, WoT, bo, nullptr, nullptr, xf, xf, nullptr, nullptr,
      nullptr, 1.f);

  ln_kernel<<<Mc, 256, 0, stream>>>(xf, ln2g, ln2b, xf, xb);

  gemm_kernel<2><<<dim3(2 * Ec / 128, Mc / 128), 256, 0, stream>>>(
      Mc, 2 * Ec, Ec, xb, W1T, b1, nullptr, nullptr, nullptr, nullptr, h1,
      nullptr, nullptr, 1.f);

  gemm_kernel<1><<<dim3(Ec / 128, Mc / 128), 256, 0, stream>>>(
      Mc, Ec, 2 * Ec, h1, W2T, b2, nullptr, nullptr, xf, (float*)d_out,
      nullptr, nullptr, nullptr, 1.f);
}

// Round 9
// 386.012 us; speedup vs baseline: 1.8329x; 1.1276x over previous
//
#include <hip/hip_runtime.h>
#include <hip/hip_bf16.h>

typedef float f32x4 __attribute__((ext_vector_type(4)));
typedef __bf16 bfv8 __attribute__((ext_vector_type(8)));

constexpr int Bc = 4, Sc = 2048, Ec = 1024, Hc = 16, Dc = 64;
constexpr int Mc = Bc * Sc;  // 8192 rows

__device__ __forceinline__ uint pkbf(float lo, float hi) {
  uint r;
  asm("v_cvt_pk_bf16_f32 %0, %1, %2" : "=v"(r) : "v"(lo), "v"(hi));
  return r;
}
__device__ __forceinline__ ushort f2bf(float f) {
  __hip_bfloat16 h = __float2bfloat16(f);
  return __builtin_bit_cast(ushort, h);
}

typedef __attribute__((address_space(1))) unsigned int as1_u32;
typedef __attribute__((address_space(3))) unsigned int as3_u32;
__device__ __forceinline__ void cp16(const ushort* g, ushort* l) {
  // async global->LDS, 16B per lane; LDS dest = wave-uniform base + lane*16
  __builtin_amdgcn_global_load_lds((as1_u32*)g, (as3_u32*)l, 16, 0, 0);
}

// ---------------- weight convert + transpose: W[K][N] f32 -> WT[N][K] bf16 ----
__global__ __launch_bounds__(256) void wcvt_kernel(const float* __restrict__ W,
                                                   ushort* __restrict__ WT,
                                                   int K, int N) {
  __shared__ float t[32][33];
  int k0 = blockIdx.x * 32, n0 = blockIdx.y * 32;
  int tx = threadIdx.x, ty = threadIdx.y;  // (32,8)
#pragma unroll
  for (int i = 0; i < 32; i += 8)
    t[ty + i][tx] = W[(size_t)(k0 + ty + i) * N + n0 + tx];
  __syncthreads();
#pragma unroll
  for (int i = 0; i < 32; i += 8)
    WT[(size_t)(n0 + ty + i) * K + k0 + tx] = f2bf(t[tx][ty + i]);
}

// ---------------- LayerNorm: row of 1024, one block per row ------------------
__global__ __launch_bounds__(256) void ln_kernel(const float* in,
                                                 const float* __restrict__ g,
                                                 const float* __restrict__ bb,
                                                 float* of, ushort* ob) {
  int row = blockIdx.x;
  int t = threadIdx.x;
  float4 x = reinterpret_cast<const float4*>(in + (size_t)row * Ec)[t];
  float s = x.x + x.y + x.z + x.w;
  float q = x.x * x.x + x.y * x.y + x.z * x.z + x.w * x.w;
#pragma unroll
  for (int o = 32; o > 0; o >>= 1) {
    s += __shfl_down(s, o);
    q += __shfl_down(q, o);
  }
  __shared__ float red[10];
  int wv = t >> 6;
  if ((t & 63) == 0) { red[wv] = s; red[4 + wv] = q; }
  __syncthreads();
  if (t == 0) {
    float S = red[0] + red[1] + red[2] + red[3];
    float Q = red[4] + red[5] + red[6] + red[7];
    float mu = S * (1.f / Ec);
    float var = Q * (1.f / Ec) - mu * mu;
    red[8] = mu;
    red[9] = rsqrtf(var + 1e-5f);
  }
  __syncthreads();
  float mu = red[8], rs = red[9];
  float4 gg = reinterpret_cast<const float4*>(g)[t];
  float4 b4 = reinterpret_cast<const float4*>(bb)[t];
  float4 y;
  y.x = (x.x - mu) * rs * gg.x + b4.x;
  y.y = (x.y - mu) * rs * gg.y + b4.y;
  y.z = (x.z - mu) * rs * gg.z + b4.z;
  y.w = (x.w - mu) * rs * gg.w + b4.w;
  reinterpret_cast<float4*>(of + (size_t)row * Ec)[t] = y;
  uint2 u;
  u.x = pkbf(y.x, y.y);
  u.y = pkbf(y.z, y.w);
  reinterpret_cast<uint2*>(ob + (size_t)row * Ec)[t] = u;
}

// ---------------- GEMM: C[M,N] = A[M,K](bf16) * BT[N,K]^T(bf16) + epilogue ---
// 128x128 tile, BK=64, LDS double-buffered, counted vmcnt(8) + raw s_barrier.
// MODE 0: fused QKV; MODE 1: f32 acc+bias+resid; MODE 2: bf16 gelu(acc+bias)
template <int MODE>
__global__ __launch_bounds__(256, 2) void gemm_kernel(
    int M, int N, int K, const ushort* __restrict__ A,
    const ushort* __restrict__ BT, const float* __restrict__ b0,
    const float* __restrict__ b1, const float* __restrict__ b2,
    const float* resid, float* outF, ushort* o0, ushort* o1, ushort* o2,
    float qscale) {
  __shared__ __align__(16) ushort As[2][128 * 64];
  __shared__ __align__(16) ushort Bs[2][128 * 64];
  const int tid = threadIdx.x;
  const int lane = tid & 63, wave = tid >> 6;
  const int wr = wave >> 1, wc = wave & 1;
  const int fr = lane & 15, fq = lane >> 4;
  const int nx = gridDim.x;
  int flat = blockIdx.x + nx * blockIdx.y;
  int cpx = (nx * gridDim.y) >> 3;
  int work = (flat & 7) * cpx + (flat >> 3);
  const int n0 = (work % nx) * 128, m0 = (work / nx) * 128;

  f32x4 acc[4][4];
#pragma unroll
  for (int i = 0; i < 4; i++)
#pragma unroll
    for (int j = 0; j < 4; j++) acc[i][j] = f32x4{0.f, 0.f, 0.f, 0.f};

  const int srow = tid >> 3;   // 0..31 (+32 per chunk)
  const int sslot = tid & 7;   // 16B slot within 128B row

  auto STAGE = [&](int p, int k0) {
#pragma unroll
    for (int c = 0; c < 4; ++c) {
      int row = c * 32 + srow;
      int scol = (sslot ^ (2 * (row & 3))) * 8;  // inverse-swizzled source
      cp16(A + (size_t)(m0 + row) * K + k0 + scol,
           &As[p][(c * 256 + wave * 64) * 8]);
      cp16(BT + (size_t)(n0 + row) * K + k0 + scol,
           &Bs[p][(c * 256 + wave * 64) * 8]);
    }
  };

  STAGE(0, 0);
  const int nt = K >> 6;
  for (int kt = 0; kt < nt; ++kt) {
    const int p = kt & 1;
    if (kt + 1 < nt) {
      STAGE(p ^ 1, (kt + 1) << 6);
      asm volatile("s_waitcnt vmcnt(8)" ::: "memory");  // tile kt landed
    } else {
      asm volatile("s_waitcnt vmcnt(0)" ::: "memory");
    }
    __builtin_amdgcn_s_barrier();
#pragma unroll
    for (int kk = 0; kk < 2; ++kk) {
      bfv8 af[4], bf[4];
#pragma unroll
      for (int m = 0; m < 4; m++) {
        int row = wr * 64 + m * 16 + fr;
        af[m] = *reinterpret_cast<const bfv8*>(
            &As[p][row * 64 + ((kk * 32 + fq * 8) ^ ((fr & 3) << 4))]);
      }
#pragma unroll
      for (int n = 0; n < 4; n++) {
        int row = wc * 64 + n * 16 + fr;
        bf[n] = *reinterpret_cast<const bfv8*>(
            &Bs[p][row * 64 + ((kk * 32 + fq * 8) ^ ((fr & 3) << 4))]);
      }
      __builtin_amdgcn_s_setprio(1);
#pragma unroll
      for (int m = 0; m < 4; m++)
#pragma unroll
        for (int n = 0; n < 4; n++)
          acc[m][n] =
              __builtin_amdgcn_mfma_f32_16x16x32_bf16(af[m], bf[n], acc[m][n], 0, 0, 0);
      __builtin_amdgcn_s_setprio(0);
    }
    __builtin_amdgcn_sched_barrier(0);
    __builtin_amdgcn_s_barrier();
  }

#pragma unroll
  for (int m = 0; m < 4; m++) {
#pragma unroll
    for (int n = 0; n < 4; n++) {
      const int row0 = m0 + wr * 64 + m * 16 + fq * 4;
      const int col = n0 + wc * 64 + n * 16 + fr;
      if constexpr (MODE == 0) {
        const int region = col >> 10, c1 = col & (Ec - 1);
        const int b = row0 >> 11, s0 = row0 & (Sc - 1);
        const int h = c1 >> 6, d = c1 & (Dc - 1);
        const float bb = (region == 0 ? b0 : region == 1 ? b1 : b2)[c1];
        if (region == 2) {
          uint2 u;
          u.x = pkbf(acc[m][n][0] + bb, acc[m][n][1] + bb);
          u.y = pkbf(acc[m][n][2] + bb, acc[m][n][3] + bb);
          *reinterpret_cast<uint2*>(
              &o2[(((size_t)b * Hc + h) * Dc + d) * Sc + s0]) = u;
        } else {
          ushort* dst = region ? o1 : o0;
          const float sc = region ? 1.f : qscale;
#pragma unroll
          for (int r = 0; r < 4; r++)
            dst[(((size_t)b * Hc + h) * Sc + s0 + r) * Dc + d] =
                f2bf((acc[m][n][r] + bb) * sc);
        }
      } else {
        const float bb = b0[col];
#pragma unroll
        for (int r = 0; r < 4; r++) {
          int row = row0 + r;
          float vacc = acc[m][n][r] + bb;
          if constexpr (MODE == 1) {
            size_t idx = (size_t)row * N + col;
            outF[idx] = vacc + resid[idx];
          } else {
            vacc = 0.5f * vacc * (1.f + erff(vacc * 0.70710678118f));
            o0[(size_t)row * N + col] = f2bf(vacc);
          }
        }
      }
    }
  }
}

// ---------------- Flash attention (32 q-rows per wave, 128 per block) --------
// q,k: [B,H,S,D] bf16 (q pre-scaled by log2e/sqrt(D)); vt: [B,H,D,S] bf16.
// Swapped QK^T; exp2-domain softmax; defer-max (THR=8 log2).
// R6 global_load_lds staging (fastest measured) + GEMM-proven schedule:
// K/V LDS DOUBLE-buffered, counted vmcnt(4) + raw s_barrier pair so tile
// t+1's loads stay in flight across the barrier (no per-tile drain).
__global__ __launch_bounds__(256) void attn_kernel(const ushort* __restrict__ q,
                                                   const ushort* __restrict__ k,
                                                   const ushort* __restrict__ vt,
                                                   ushort* __restrict__ o) {
  int flat = blockIdx.x;                     // 1024 blocks
  int swz = (flat & 7) * 128 + (flat >> 3);  // XCD-chunked: 8 heads per XCD
  const int qb = swz & 15;                   // 16 q-blocks of 128 rows
  const int bh = swz >> 4;
  const int tid = threadIdx.x, lane = tid & 63, wave = tid >> 6;
  const int fr = lane & 15, fq = lane >> 4;
  const size_t base = (size_t)bh * Sc * Dc;
  const int q0 = qb * 128 + wave * 32;

  __shared__ __align__(16) ushort Ks[2][64 * 64];  // [key][d], XOR-swizzled
  __shared__ __align__(16) ushort Vt[2][64 * 64];  // [d][key], XOR-swizzled
  __shared__ __align__(16) ushort Ps[4][16 * 72];  // per-wave P tile

  bfv8 qf0[2], qf1[2];
#pragma unroll
  for (int f = 0; f < 2; ++f) {
    const ushort* qp = q + base + (size_t)(q0 + f * 16 + fr) * Dc + fq * 8;
    qf0[f] = *reinterpret_cast<const bfv8*>(qp);
    qf1[f] = *reinterpret_cast<const bfv8*>(qp + 32);
  }

  f32x4 oacc[2][4];  // [frag][dtile]
#pragma unroll
  for (int f = 0; f < 2; ++f)
#pragma unroll
    for (int d = 0; d < 4; ++d) oacc[f][d] = f32x4{0.f, 0.f, 0.f, 0.f};
  float mrow[2] = {-3e38f, -3e38f};
  float lrow[2] = {0.f, 0.f};

  const int r8 = tid >> 3;  // staging row 0..31
  const int c8 = tid & 7;   // staging 16B chunk

  auto STAGE = [&](int p, int key0) {
#pragma unroll
    for (int i = 0; i < 2; ++i) {
      int row = i * 32 + r8;
      int sc = (c8 ^ (row & 7)) * 8;  // inverse-swizzled source
      cp16(k + base + (size_t)(key0 + row) * Dc + sc,
           &Ks[p][i * 2048 + wave * 512]);
      cp16(vt + base + (size_t)row * Sc + key0 + sc,
           &Vt[p][i * 2048 + wave * 512]);
    }
  };

  const int sA = (fq ^ (fr & 7)) * 8;        // swizzled read offset, chunks 0-3
  const int sB = ((fq + 4) ^ (fr & 7)) * 8;  // chunks 4-7

  STAGE(0, 0);
  constexpr int NT = Sc / 64;
  for (int kt = 0; kt < NT; ++kt) {
    const int p = kt & 1;
    if (kt + 1 < NT) {
      STAGE(p ^ 1, (kt + 1) * 64);  // 4 loads for tile kt+1 stay in flight
      asm volatile("s_waitcnt vmcnt(4)" ::: "memory");  // tile kt landed
    } else {
      asm volatile("s_waitcnt vmcnt(0)" ::: "memory");
    }
    __builtin_amdgcn_s_barrier();

    bfv8 kf0[4], kf1[4], vf0[4], vf1[4];
#pragma unroll
    for (int t = 0; t < 4; ++t) {
      int e = (t * 16 + fr) * 64;
      kf0[t] = *reinterpret_cast<const bfv8*>(&Ks[p][e + sA]);
      kf1[t] = *reinterpret_cast<const bfv8*>(&Ks[p][e + sB]);
      vf0[t] = *reinterpret_cast<const bfv8*>(&Vt[p][e + sA]);
      vf1[t] = *reinterpret_cast<const bfv8*>(&Vt[p][e + sB]);
    }

#pragma unroll
    for (int f = 0; f < 2; ++f) {
      f32x4 sf[4];
      __builtin_amdgcn_s_setprio(1);
#pragma unroll
      for (int t = 0; t < 4; ++t) {
        sf[t] = f32x4{0.f, 0.f, 0.f, 0.f};
        sf[t] = __builtin_amdgcn_mfma_f32_16x16x32_bf16(kf0[t], qf0[f], sf[t], 0, 0, 0);
        sf[t] = __builtin_amdgcn_mfma_f32_16x16x32_bf16(kf1[t], qf1[f], sf[t], 0, 0, 0);
      }
      __builtin_amdgcn_s_setprio(0);
      // lane holds S[q=fr][key = t*16 + fq*4 + r], log2 domain
      float mt0 = fmaxf(fmaxf(sf[0][0], sf[0][1]), fmaxf(sf[0][2], sf[0][3]));
      float mt1 = fmaxf(fmaxf(sf[1][0], sf[1][1]), fmaxf(sf[1][2], sf[1][3]));
      float mt2 = fmaxf(fmaxf(sf[2][0], sf[2][1]), fmaxf(sf[2][2], sf[2][3]));
      float mt3 = fmaxf(fmaxf(sf[3][0], sf[3][1]), fmaxf(sf[3][2], sf[3][3]));
      float pmax = fmaxf(fmaxf(mt0, mt1), fmaxf(mt2, mt3));
      float m = mrow[f];
      float mnew = m;
      if (!__all(pmax <= m + 8.f)) {
        float mt = fmaxf(pmax, __shfl_xor(pmax, 16));
        mt = fmaxf(mt, __shfl_xor(mt, 32));
        mnew = fmaxf(m, mt);
        float alpha = __builtin_amdgcn_exp2f(m - mnew);
        float ar[4];
#pragma unroll
        for (int r = 0; r < 4; ++r) ar[r] = __shfl(alpha, fq * 4 + r);
#pragma unroll
        for (int d = 0; d < 4; ++d)
#pragma unroll
          for (int r = 0; r < 4; ++r) oacc[f][d][r] *= ar[r];
        lrow[f] *= alpha;
        mrow[f] = mnew;
      }
      float p4[4][4];
      float rsum = 0.f;
#pragma unroll
      for (int t = 0; t < 4; ++t) {
#pragma unroll
        for (int r = 0; r < 4; ++r) {
          p4[t][r] = __builtin_amdgcn_exp2f(sf[t][r] - mnew);
        }
        rsum += (p4[t][0] + p4[t][1]) + (p4[t][2] + p4[t][3]);
      }
      rsum += __shfl_xor(rsum, 16);
      rsum += __shfl_xor(rsum, 32);
      lrow[f] += rsum;
      ushort* pw = &Ps[wave][0];
#pragma unroll
      for (int t = 0; t < 4; ++t) {
        uint2 pu;
        pu.x = pkbf(p4[t][0], p4[t][1]);
        pu.y = pkbf(p4[t][2], p4[t][3]);
        *reinterpret_cast<uint2*>(&pw[fr * 72 + t * 16 + fq * 4]) = pu;
      }
      bfv8 pf0 = *reinterpret_cast<const bfv8*>(&pw[fr * 72 + fq * 8]);
      bfv8 pf1 = *reinterpret_cast<const bfv8*>(&pw[fr * 72 + 32 + fq * 8]);
      __builtin_amdgcn_s_setprio(1);
#pragma unroll
      for (int d = 0; d < 4; ++d) {
        oacc[f][d] = __builtin_amdgcn_mfma_f32_16x16x32_bf16(pf0, vf0[d], oacc[f][d], 0, 0, 0);
        oacc[f][d] = __builtin_amdgcn_mfma_f32_16x16x32_bf16(pf1, vf1[d], oacc[f][d], 0, 0, 0);
      }
      __builtin_amdgcn_s_setprio(0);
    }
    __builtin_amdgcn_sched_barrier(0);
    __builtin_amdgcn_s_barrier();
  }

  const int b = bh >> 4, h = bh & 15;
#pragma unroll
  for (int f = 0; f < 2; ++f) {
    float linv[4];
#pragma unroll
    for (int r = 0; r < 4; ++r) linv[r] = 1.f / __shfl(lrow[f], fq * 4 + r);
#pragma unroll
    for (int d = 0; d < 4; ++d)
#pragma unroll
      for (int r = 0; r < 4; ++r) {
        int sIdx = q0 + f * 16 + fq * 4 + r;
        o[((size_t)(b * Sc + sIdx)) * Ec + h * 64 + d * 16 + fr] =
            f2bf(oacc[f][d][r] * linv[r]);
      }
  }
}

// -----------------------------------------------------------------------------
extern "C" void kernel_launch(void* const* d_in, const int* in_sizes, int n_in,
                              void* d_out, int out_size, void* d_ws, size_t ws_size,
                              hipStream_t stream) {
  const float* inp = (const float*)d_in[0];
  const float* ln1g = (const float*)d_in[1];
  const float* ln1b = (const float*)d_in[2];
  const float* Wq = (const float*)d_in[3];
  const float* bq = (const float*)d_in[4];
  const float* Wk = (const float*)d_in[5];
  const float* bk = (const float*)d_in[6];
  const float* Wv = (const float*)d_in[7];
  const float* bv = (const float*)d_in[8];
  const float* Wo = (const float*)d_in[9];
  const float* bo = (const float*)d_in[10];
  const float* ln2g = (const float*)d_in[11];
  const float* ln2b = (const float*)d_in[12];
  const float* W1 = (const float*)d_in[13];
  const float* b1 = (const float*)d_in[14];
  const float* W2 = (const float*)d_in[15];
  const float* b2 = (const float*)d_in[16];

  char* wsb = (char*)d_ws;
  size_t off = 0;
  auto alloc = [&](size_t bytes) {
    char* p = wsb + off;
    off += (bytes + 255) & ~(size_t)255;
    return p;
  };
  float* xf = (float*)alloc((size_t)Mc * Ec * 4);
  ushort* xb = (ushort*)alloc((size_t)Mc * Ec * 2);
  ushort* qbuf = (ushort*)alloc((size_t)Mc * Ec * 2);
  ushort* kbuf = (ushort*)alloc((size_t)Mc * Ec * 2);
  ushort* vtbuf = (ushort*)alloc((size_t)Mc * Ec * 2);
  ushort* abuf = (ushort*)alloc((size_t)Mc * Ec * 2);
  ushort* h1 = (ushort*)alloc((size_t)Mc * 2 * Ec * 2);
  ushort* WqkvT = (ushort*)alloc((size_t)3 * Ec * Ec * 2);  // [3E][E]
  ushort* WoT = (ushort*)alloc((size_t)Ec * Ec * 2);
  ushort* W1T = (ushort*)alloc((size_t)Ec * 2 * Ec * 2);
  ushort* W2T = (ushort*)alloc((size_t)Ec * 2 * Ec * 2);
  (void)in_sizes; (void)n_in; (void)out_size; (void)ws_size;

  dim3 tb(32, 8);
  wcvt_kernel<<<dim3(Ec / 32, Ec / 32), tb, 0, stream>>>(Wq, WqkvT, Ec, Ec);
  wcvt_kernel<<<dim3(Ec / 32, Ec / 32), tb, 0, stream>>>(Wk, WqkvT + (size_t)Ec * Ec, Ec, Ec);
  wcvt_kernel<<<dim3(Ec / 32, Ec / 32), tb, 0, stream>>>(Wv, WqkvT + (size_t)2 * Ec * Ec, Ec, Ec);
  wcvt_kernel<<<dim3(Ec / 32, Ec / 32), tb, 0, stream>>>(Wo, WoT, Ec, Ec);
  wcvt_kernel<<<dim3(Ec / 32, 2 * Ec / 32), tb, 0, stream>>>(W1, W1T, Ec, 2 * Ec);
  wcvt_kernel<<<dim3(2 * Ec / 32, Ec / 32), tb, 0, stream>>>(W2, W2T, 2 * Ec, Ec);

  ln_kernel<<<Mc, 256, 0, stream>>>(inp, ln1g, ln1b, xf, xb);

  // Fused QKV: N=3072. Q pre-scale (1/sqrt(D))*log2(e) -> exp2-domain softmax
  gemm_kernel<0><<<dim3(3 * Ec / 128, Mc / 128), 256, 0, stream>>>(
      Mc, 3 * Ec, Ec, xb, WqkvT, bq, bk, bv, nullptr, nullptr, qbuf, kbuf,
      vtbuf, 0.18033688f);

  attn_kernel<<<Bc * Hc * (Sc / 128), 256, 0, stream>>>(qbuf, kbuf, vtbuf, abuf);

  gemm_kernel<1><<<dim3(Ec / 128, Mc / 128), 256, 0, stream>>>(
      Mc, Ec, Ec, abuf, WoT, bo, nullptr, nullptr, xf, xf, nullptr, nullptr,
      nullptr, 1.f);

  ln_kernel<<<Mc, 256, 0, stream>>>(xf, ln2g, ln2b, xf, xb);

  gemm_kernel<2><<<dim3(2 * Ec / 128, Mc / 128), 256, 0, stream>>>(
      Mc, 2 * Ec, Ec, xb, W1T, b1, nullptr, nullptr, nullptr, nullptr, h1,
      nullptr, nullptr, 1.f);

  gemm_kernel<1><<<dim3(Ec / 128, Mc / 128), 256, 0, stream>>>(
      Mc, Ec, 2 * Ec, h1, W2T, b2, nullptr, nullptr, xf, (float*)d_out,
      nullptr, nullptr, nullptr, 1.f);
}

// Round 11
// 379.250 us; speedup vs baseline: 1.8656x; 1.0178x over previous
//
#include <hip/hip_runtime.h>
#include <hip/hip_bf16.h>

typedef float f32x4 __attribute__((ext_vector_type(4)));
typedef __bf16 bfv8 __attribute__((ext_vector_type(8)));

constexpr int Bc = 4, Sc = 2048, Ec = 1024, Hc = 16, Dc = 64;
constexpr int Mc = Bc * Sc;  // 8192 rows

__device__ __forceinline__ uint pkbf(float lo, float hi) {
  uint r;
  asm("v_cvt_pk_bf16_f32 %0, %1, %2" : "=v"(r) : "v"(lo), "v"(hi));
  return r;
}
__device__ __forceinline__ ushort f2bf(float f) {
  __hip_bfloat16 h = __float2bfloat16(f);
  return __builtin_bit_cast(ushort, h);
}

typedef __attribute__((address_space(1))) unsigned int as1_u32;
typedef __attribute__((address_space(3))) unsigned int as3_u32;
__device__ __forceinline__ void cp16(const ushort* g, ushort* l) {
  // async global->LDS, 16B per lane; LDS dest = wave-uniform base + lane*16
  __builtin_amdgcn_global_load_lds((as1_u32*)g, (as3_u32*)l, 16, 0, 0);
}

// ---------------- weight convert + transpose: W[K][N] f32 -> WT[N][K] bf16 ----
__global__ __launch_bounds__(256) void wcvt_kernel(const float* __restrict__ W,
                                                   ushort* __restrict__ WT,
                                                   int K, int N) {
  __shared__ float t[32][33];
  int k0 = blockIdx.x * 32, n0 = blockIdx.y * 32;
  int tx = threadIdx.x, ty = threadIdx.y;  // (32,8)
#pragma unroll
  for (int i = 0; i < 32; i += 8)
    t[ty + i][tx] = W[(size_t)(k0 + ty + i) * N + n0 + tx];
  __syncthreads();
#pragma unroll
  for (int i = 0; i < 32; i += 8)
    WT[(size_t)(n0 + ty + i) * K + k0 + tx] = f2bf(t[tx][ty + i]);
}

// ---------------- LayerNorm: row of 1024, one block per row ------------------
__global__ __launch_bounds__(256) void ln_kernel(const float* in,
                                                 const float* __restrict__ g,
                                                 const float* __restrict__ bb,
                                                 float* of, ushort* ob) {
  int row = blockIdx.x;
  int t = threadIdx.x;
  float4 x = reinterpret_cast<const float4*>(in + (size_t)row * Ec)[t];
  float s = x.x + x.y + x.z + x.w;
  float q = x.x * x.x + x.y * x.y + x.z * x.z + x.w * x.w;
#pragma unroll
  for (int o = 32; o > 0; o >>= 1) {
    s += __shfl_down(s, o);
    q += __shfl_down(q, o);
  }
  __shared__ float red[10];
  int wv = t >> 6;
  if ((t & 63) == 0) { red[wv] = s; red[4 + wv] = q; }
  __syncthreads();
  if (t == 0) {
    float S = red[0] + red[1] + red[2] + red[3];
    float Q = red[4] + red[5] + red[6] + red[7];
    float mu = S * (1.f / Ec);
    float var = Q * (1.f / Ec) - mu * mu;
    red[8] = mu;
    red[9] = rsqrtf(var + 1e-5f);
  }
  __syncthreads();
  float mu = red[8], rs = red[9];
  float4 gg = reinterpret_cast<const float4*>(g)[t];
  float4 b4 = reinterpret_cast<const float4*>(bb)[t];
  float4 y;
  y.x = (x.x - mu) * rs * gg.x + b4.x;
  y.y = (x.y - mu) * rs * gg.y + b4.y;
  y.z = (x.z - mu) * rs * gg.z + b4.z;
  y.w = (x.w - mu) * rs * gg.w + b4.w;
  reinterpret_cast<float4*>(of + (size_t)row * Ec)[t] = y;
  uint2 u;
  u.x = pkbf(y.x, y.y);
  u.y = pkbf(y.z, y.w);
  reinterpret_cast<uint2*>(ob + (size_t)row * Ec)[t] = u;
}

// ---------------- GEMM: C[M,N] = A[M,K](bf16) * BT[N,K]^T(bf16) + epilogue ---
// 128x128 tile, BK=64, LDS double-buffered, counted vmcnt(8) + raw s_barrier.
// MODE 0: fused QKV; MODE 1: f32 acc+bias+resid; MODE 2: bf16 gelu(acc+bias)
template <int MODE>
__global__ __launch_bounds__(256, 2) void gemm_kernel(
    int M, int N, int K, const ushort* __restrict__ A,
    const ushort* __restrict__ BT, const float* __restrict__ b0,
    const float* __restrict__ b1, const float* __restrict__ b2,
    const float* resid, float* outF, ushort* o0, ushort* o1, ushort* o2,
    float qscale) {
  __shared__ __align__(16) ushort As[2][128 * 64];
  __shared__ __align__(16) ushort Bs[2][128 * 64];
  const int tid = threadIdx.x;
  const int lane = tid & 63, wave = tid >> 6;
  const int wr = wave >> 1, wc = wave & 1;
  const int fr = lane & 15, fq = lane >> 4;
  const int nx = gridDim.x;
  int flat = blockIdx.x + nx * blockIdx.y;
  int cpx = (nx * gridDim.y) >> 3;
  int work = (flat & 7) * cpx + (flat >> 3);
  const int n0 = (work % nx) * 128, m0 = (work / nx) * 128;

  f32x4 acc[4][4];
#pragma unroll
  for (int i = 0; i < 4; i++)
#pragma unroll
    for (int j = 0; j < 4; j++) acc[i][j] = f32x4{0.f, 0.f, 0.f, 0.f};

  const int srow = tid >> 3;   // 0..31 (+32 per chunk)
  const int sslot = tid & 7;   // 16B slot within 128B row

  auto STAGE = [&](int p, int k0) {
#pragma unroll
    for (int c = 0; c < 4; ++c) {
      int row = c * 32 + srow;
      int scol = (sslot ^ (2 * (row & 3))) * 8;  // inverse-swizzled source
      cp16(A + (size_t)(m0 + row) * K + k0 + scol,
           &As[p][(c * 256 + wave * 64) * 8]);
      cp16(BT + (size_t)(n0 + row) * K + k0 + scol,
           &Bs[p][(c * 256 + wave * 64) * 8]);
    }
  };

  STAGE(0, 0);
  const int nt = K >> 6;
  for (int kt = 0; kt < nt; ++kt) {
    const int p = kt & 1;
    if (kt + 1 < nt) {
      STAGE(p ^ 1, (kt + 1) << 6);
      asm volatile("s_waitcnt vmcnt(8)" ::: "memory");  // tile kt landed
    } else {
      asm volatile("s_waitcnt vmcnt(0)" ::: "memory");
    }
    __builtin_amdgcn_s_barrier();
#pragma unroll
    for (int kk = 0; kk < 2; ++kk) {
      bfv8 af[4], bf[4];
#pragma unroll
      for (int m = 0; m < 4; m++) {
        int row = wr * 64 + m * 16 + fr;
        af[m] = *reinterpret_cast<const bfv8*>(
            &As[p][row * 64 + ((kk * 32 + fq * 8) ^ ((fr & 3) << 4))]);
      }
#pragma unroll
      for (int n = 0; n < 4; n++) {
        int row = wc * 64 + n * 16 + fr;
        bf[n] = *reinterpret_cast<const bfv8*>(
            &Bs[p][row * 64 + ((kk * 32 + fq * 8) ^ ((fr & 3) << 4))]);
      }
      __builtin_amdgcn_s_setprio(1);
#pragma unroll
      for (int m = 0; m < 4; m++)
#pragma unroll
        for (int n = 0; n < 4; n++)
          acc[m][n] =
              __builtin_amdgcn_mfma_f32_16x16x32_bf16(af[m], bf[n], acc[m][n], 0, 0, 0);
      __builtin_amdgcn_s_setprio(0);
    }
    __builtin_amdgcn_sched_barrier(0);
    __builtin_amdgcn_s_barrier();
  }

#pragma unroll
  for (int m = 0; m < 4; m++) {
#pragma unroll
    for (int n = 0; n < 4; n++) {
      const int row0 = m0 + wr * 64 + m * 16 + fq * 4;
      const int col = n0 + wc * 64 + n * 16 + fr;
      if constexpr (MODE == 0) {
        const int region = col >> 10, c1 = col & (Ec - 1);
        const int b = row0 >> 11, s0 = row0 & (Sc - 1);
        const int h = c1 >> 6, d = c1 & (Dc - 1);
        const float bb = (region == 0 ? b0 : region == 1 ? b1 : b2)[c1];
        if (region == 2) {
          uint2 u;
          u.x = pkbf(acc[m][n][0] + bb, acc[m][n][1] + bb);
          u.y = pkbf(acc[m][n][2] + bb, acc[m][n][3] + bb);
          *reinterpret_cast<uint2*>(
              &o2[(((size_t)b * Hc + h) * Dc + d) * Sc + s0]) = u;
        } else {
          ushort* dst = region ? o1 : o0;
          const float sc = region ? 1.f : qscale;
#pragma unroll
          for (int r = 0; r < 4; r++)
            dst[(((size_t)b * Hc + h) * Sc + s0 + r) * Dc + d] =
                f2bf((acc[m][n][r] + bb) * sc);
        }
      } else {
        const float bb = b0[col];
#pragma unroll
        for (int r = 0; r < 4; r++) {
          int row = row0 + r;
          float vacc = acc[m][n][r] + bb;
          if constexpr (MODE == 1) {
            size_t idx = (size_t)row * N + col;
            outF[idx] = vacc + resid[idx];
          } else {
            vacc = 0.5f * vacc * (1.f + erff(vacc * 0.70710678118f));
            o0[(size_t)row * N + col] = f2bf(vacc);
          }
        }
      }
    }
  }
}

// ---------------- Flash attention (32 q-rows per wave, 128 per block) --------
// q,k: [B,H,S,D] bf16 (q pre-scaled by log2e/sqrt(D)); vt: [B,H,D,S] bf16.
// Swapped QK^T; exp2-domain softmax; defer-max (THR=8 log2).
// K/V LDS double-buffered + counted vmcnt(4) + raw barriers (R9 schedule).
// l-sum via MFMA with all-ones B fragment (no rsum adds/shuffles).
// P round-trips a pad-free XOR-swizzled per-wave LDS tile [16][64]
// (unit u = t*4+fq, swz u^(2*(fr&7)); 2-way write conflicts = free).
// LDS total = 40960 B = exactly 4 blocks/CU.
__global__ __launch_bounds__(256) void attn_kernel(const ushort* __restrict__ q,
                                                   const ushort* __restrict__ k,
                                                   const ushort* __restrict__ vt,
                                                   ushort* __restrict__ o) {
  int flat = blockIdx.x;                     // 1024 blocks
  int swz = (flat & 7) * 128 + (flat >> 3);  // XCD-chunked: 8 heads per XCD
  const int qb = swz & 15;                   // 16 q-blocks of 128 rows
  const int bh = swz >> 4;
  const int tid = threadIdx.x, lane = tid & 63, wave = tid >> 6;
  const int fr = lane & 15, fq = lane >> 4;
  const size_t base = (size_t)bh * Sc * Dc;
  const int q0 = qb * 128 + wave * 32;

  __shared__ __align__(16) ushort Ks[2][64 * 64];  // [key][d], XOR-swizzled
  __shared__ __align__(16) ushort Vt[2][64 * 64];  // [d][key], XOR-swizzled
  __shared__ __align__(16) ushort Ps[4][16 * 64];  // per-wave P, XOR-swizzled

  bfv8 qf0[2], qf1[2];
#pragma unroll
  for (int f = 0; f < 2; ++f) {
    const ushort* qp = q + base + (size_t)(q0 + f * 16 + fr) * Dc + fq * 8;
    qf0[f] = *reinterpret_cast<const bfv8*>(qp);
    qf1[f] = *reinterpret_cast<const bfv8*>(qp + 32);
  }

  // all-ones bf16 B-fragment for the l-sum MFMA
  const bfv8 ones = __builtin_bit_cast(bfv8, uint4{0x3F803F80u, 0x3F803F80u,
                                                  0x3F803F80u, 0x3F803F80u});

  f32x4 oacc[2][4];  // [frag][dtile]
  f32x4 oaccL[2];    // row-sum accumulator (l), replicated over cols
#pragma unroll
  for (int f = 0; f < 2; ++f) {
    oaccL[f] = f32x4{0.f, 0.f, 0.f, 0.f};
#pragma unroll
    for (int d = 0; d < 4; ++d) oacc[f][d] = f32x4{0.f, 0.f, 0.f, 0.f};
  }
  float mrow[2] = {-3e38f, -3e38f};

  const int r8 = tid >> 3;  // staging row 0..31
  const int c8 = tid & 7;   // staging 16B chunk

  auto STAGE = [&](int p, int key0) {
#pragma unroll
    for (int i = 0; i < 2; ++i) {
      int row = i * 32 + r8;
      int sc = (c8 ^ (row & 7)) * 8;  // inverse-swizzled source
      cp16(k + base + (size_t)(key0 + row) * Dc + sc,
           &Ks[p][i * 2048 + wave * 512]);
      cp16(vt + base + (size_t)row * Sc + key0 + sc,
           &Vt[p][i * 2048 + wave * 512]);
    }
  };

  const int sA = (fq ^ (fr & 7)) * 8;        // swizzled read offset, chunks 0-3
  const int sB = ((fq + 4) ^ (fr & 7)) * 8;  // chunks 4-7

  // Ps swizzled offsets (ushort units): row base fr*64, unit = 4 ushorts
  const int pswz = 2 * (fr & 7);
  const int pr0 = fr * 64 + ((fq * 2) ^ pswz) * 4;      // keys 0..31 frag
  const int pr1 = fr * 64 + ((fq * 2 + 8) ^ pswz) * 4;  // keys 32..63 frag

  STAGE(0, 0);
  constexpr int NT = Sc / 64;
  for (int kt = 0; kt < NT; ++kt) {
    const int p = kt & 1;
    if (kt + 1 < NT) {
      STAGE(p ^ 1, (kt + 1) * 64);  // 4 loads for tile kt+1 stay in flight
      asm volatile("s_waitcnt vmcnt(4)" ::: "memory");  // tile kt landed
    } else {
      asm volatile("s_waitcnt vmcnt(0)" ::: "memory");
    }
    __builtin_amdgcn_s_barrier();

    bfv8 kf0[4], kf1[4], vf0[4], vf1[4];
#pragma unroll
    for (int t = 0; t < 4; ++t) {
      int e = (t * 16 + fr) * 64;
      kf0[t] = *reinterpret_cast<const bfv8*>(&Ks[p][e + sA]);
      kf1[t] = *reinterpret_cast<const bfv8*>(&Ks[p][e + sB]);
      vf0[t] = *reinterpret_cast<const bfv8*>(&Vt[p][e + sA]);
      vf1[t] = *reinterpret_cast<const bfv8*>(&Vt[p][e + sB]);
    }

#pragma unroll
    for (int f = 0; f < 2; ++f) {
      f32x4 sf[4];
      __builtin_amdgcn_s_setprio(1);
#pragma unroll
      for (int t = 0; t < 4; ++t) {
        sf[t] = f32x4{0.f, 0.f, 0.f, 0.f};
        sf[t] = __builtin_amdgcn_mfma_f32_16x16x32_bf16(kf0[t], qf0[f], sf[t], 0, 0, 0);
        sf[t] = __builtin_amdgcn_mfma_f32_16x16x32_bf16(kf1[t], qf1[f], sf[t], 0, 0, 0);
      }
      __builtin_amdgcn_s_setprio(0);
      // lane holds S[q=fr][key = t*16 + fq*4 + r], log2 domain
      float mt0 = fmaxf(fmaxf(sf[0][0], sf[0][1]), fmaxf(sf[0][2], sf[0][3]));
      float mt1 = fmaxf(fmaxf(sf[1][0], sf[1][1]), fmaxf(sf[1][2], sf[1][3]));
      float mt2 = fmaxf(fmaxf(sf[2][0], sf[2][1]), fmaxf(sf[2][2], sf[2][3]));
      float mt3 = fmaxf(fmaxf(sf[3][0], sf[3][1]), fmaxf(sf[3][2], sf[3][3]));
      float pmax = fmaxf(fmaxf(mt0, mt1), fmaxf(mt2, mt3));
      float m = mrow[f];
      float mnew = m;
      if (!__all(pmax <= m + 8.f)) {
        float mt = fmaxf(pmax, __shfl_xor(pmax, 16));
        mt = fmaxf(mt, __shfl_xor(mt, 32));
        mnew = fmaxf(m, mt);
        float alpha = __builtin_amdgcn_exp2f(m - mnew);
        float ar[4];
#pragma unroll
        for (int r = 0; r < 4; ++r) ar[r] = __shfl(alpha, fq * 4 + r);
#pragma unroll
        for (int d = 0; d < 4; ++d)
#pragma unroll
          for (int r = 0; r < 4; ++r) oacc[f][d][r] *= ar[r];
#pragma unroll
        for (int r = 0; r < 4; ++r) oaccL[f][r] *= ar[r];
        mrow[f] = mnew;
      }
      ushort* pw = &Ps[wave][0];
#pragma unroll
      for (int t = 0; t < 4; ++t) {
        uint2 pu;
        pu.x = pkbf(__builtin_amdgcn_exp2f(sf[t][0] - mnew),
                    __builtin_amdgcn_exp2f(sf[t][1] - mnew));
        pu.y = pkbf(__builtin_amdgcn_exp2f(sf[t][2] - mnew),
                    __builtin_amdgcn_exp2f(sf[t][3] - mnew));
        int us = fr * 64 + ((t * 4 + fq) ^ pswz) * 4;
        *reinterpret_cast<uint2*>(&pw[us]) = pu;
      }
      bfv8 pf0 = *reinterpret_cast<const bfv8*>(&pw[pr0]);
      bfv8 pf1 = *reinterpret_cast<const bfv8*>(&pw[pr1]);
      __builtin_amdgcn_s_setprio(1);
#pragma unroll
      for (int d = 0; d < 4; ++d) {
        oacc[f][d] = __builtin_amdgcn_mfma_f32_16x16x32_bf16(pf0, vf0[d], oacc[f][d], 0, 0, 0);
        oacc[f][d] = __builtin_amdgcn_mfma_f32_16x16x32_bf16(pf1, vf1[d], oacc[f][d], 0, 0, 0);
      }
      oaccL[f] = __builtin_amdgcn_mfma_f32_16x16x32_bf16(pf0, ones, oaccL[f], 0, 0, 0);
      oaccL[f] = __builtin_amdgcn_mfma_f32_16x16x32_bf16(pf1, ones, oaccL[f], 0, 0, 0);
      __builtin_amdgcn_s_setprio(0);
    }
    __builtin_amdgcn_sched_barrier(0);
    __builtin_amdgcn_s_barrier();
  }

  const int b = bh >> 4, h = bh & 15;
#pragma unroll
  for (int f = 0; f < 2; ++f) {
    float linv[4];
#pragma unroll
    for (int r = 0; r < 4; ++r) linv[r] = 1.f / oaccL[f][r];
#pragma unroll
    for (int d = 0; d < 4; ++d)
#pragma unroll
      for (int r = 0; r < 4; ++r) {
        int sIdx = q0 + f * 16 + fq * 4 + r;
        o[((size_t)(b * Sc + sIdx)) * Ec + h * 64 + d * 16 + fr] =
            f2bf(oacc[f][d][r] * linv[r]);
      }
  }
}

// -----------------------------------------------------------------------------
extern "C" void kernel_launch(void* const* d_in, const int* in_sizes, int n_in,
                              void* d_out, int out_size, void* d_ws, size_t ws_size,
                              hipStream_t stream) {
  const float* inp = (const float*)d_in[0];
  const float* ln1g = (const float*)d_in[1];
  const float* ln1b = (const float*)d_in[2];
  const float* Wq = (const float*)d_in[3];
  const float* bq = (const float*)d_in[4];
  const float* Wk = (const float*)d_in[5];
  const float* bk = (const float*)d_in[6];
  const float* Wv = (const float*)d_in[7];
  const float* bv = (const float*)d_in[8];
  const float* Wo = (const float*)d_in[9];
  const float* bo = (const float*)d_in[10];
  const float* ln2g = (const float*)d_in[11];
  const float* ln2b = (const float*)d_in[12];
  const float* W1 = (const float*)d_in[13];
  const float* b1 = (const float*)d_in[14];
  const float* W2 = (const float*)d_in[15];
  const float* b2 = (const float*)d_in[16];

  char* wsb = (char*)d_ws;
  size_t off = 0;
  auto alloc = [&](size_t bytes) {
    char* p = wsb + off;
    off += (bytes + 255) & ~(size_t)255;
    return p;
  };
  float* xf = (float*)alloc((size_t)Mc * Ec * 4);
  ushort* xb = (ushort*)alloc((size_t)Mc * Ec * 2);
  ushort* qbuf = (ushort*)alloc((size_t)Mc * Ec * 2);
  ushort* kbuf = (ushort*)alloc((size_t)Mc * Ec * 2);
  ushort* vtbuf = (ushort*)alloc((size_t)Mc * Ec * 2);
  ushort* abuf = (ushort*)alloc((size_t)Mc * Ec * 2);
  ushort* h1 = (ushort*)alloc((size_t)Mc * 2 * Ec * 2);
  ushort* WqkvT = (ushort*)alloc((size_t)3 * Ec * Ec * 2);  // [3E][E]
  ushort* WoT = (ushort*)alloc((size_t)Ec * Ec * 2);
  ushort* W1T = (ushort*)alloc((size_t)Ec * 2 * Ec * 2);
  ushort* W2T = (ushort*)alloc((size_t)Ec * 2 * Ec * 2);
  (void)in_sizes; (void)n_in; (void)out_size; (void)ws_size;

  dim3 tb(32, 8);
  wcvt_kernel<<<dim3(Ec / 32, Ec / 32), tb, 0, stream>>>(Wq, WqkvT, Ec, Ec);
  wcvt_kernel<<<dim3(Ec / 32, Ec / 32), tb, 0, stream>>>(Wk, WqkvT + (size_t)Ec * Ec, Ec, Ec);
  wcvt_kernel<<<dim3(Ec / 32, Ec / 32), tb, 0, stream>>>(Wv, WqkvT + (size_t)2 * Ec * Ec, Ec, Ec);
  wcvt_kernel<<<dim3(Ec / 32, Ec / 32), tb, 0, stream>>>(Wo, WoT, Ec, Ec);
  wcvt_kernel<<<dim3(Ec / 32, 2 * Ec / 32), tb, 0, stream>>>(W1, W1T, Ec, 2 * Ec);
  wcvt_kernel<<<dim3(2 * Ec / 32, Ec / 32), tb, 0, stream>>>(W2, W2T, 2 * Ec, Ec);

  ln_kernel<<<Mc, 256, 0, stream>>>(inp, ln1g, ln1b, xf, xb);

  // Fused QKV: N=3072. Q pre-scale (1/sqrt(D))*log2(e) -> exp2-domain softmax
  gemm_kernel<0><<<dim3(3 * Ec / 128, Mc / 128), 256, 0, stream>>>(
      Mc, 3 * Ec, Ec, xb, WqkvT, bq, bk, bv, nullptr, nullptr, qbuf, kbuf,
      vtbuf, 0.18033688f);

  attn_kernel<<<Bc * Hc * (Sc / 128), 256, 0, stream>>>(qbuf, kbuf, vtbuf, abuf);

  gemm_kernel<1><<<dim3(Ec / 128, Mc / 128), 256, 0, stream>>>(
      Mc, Ec, Ec, abuf, WoT, bo, nullptr, nullptr, xf, xf, nullptr, nullptr,
      nullptr, 1.f);

  ln_kernel<<<Mc, 256, 0, stream>>>(xf, ln2g, ln2b, xf, xb);

  gemm_kernel<2><<<dim3(2 * Ec / 128, Mc / 128), 256, 0, stream>>>(
      Mc, 2 * Ec, Ec, xb, W1T, b1, nullptr, nullptr, nullptr, nullptr, h1,
      nullptr, nullptr, 1.f);

  gemm_kernel<1><<<dim3(Ec / 128, Mc / 128), 256, 0, stream>>>(
      Mc, Ec, 2 * Ec, h1, W2T, b2, nullptr, nullptr, xf, (float*)d_out,
      nullptr, nullptr, nullptr, 1.f);
}